// Round 1
// baseline (98.767 us; speedup 1.0000x reference)
//
#include <hip/hip_runtime.h>

// LSEP: loss = mean_i log1p( (sum_{n: partial=0} exp(q_n)) * (sum_{p: partial=1} exp(-q_p)) )
// where q = T[i, bayes[i], :],  T: [B, C, C] f32, bayes: [B] int, partial: [B, C] int.
// B = 1e6, C = 10. Memory-bound gather + scalar reduce.

#define NROWS 1000000
#define C 10

__global__ __launch_bounds__(256) void lsep_kernel(const float* __restrict__ T,
                                                   const int* __restrict__ bayes,
                                                   const int* __restrict__ partial,
                                                   float* __restrict__ out,
                                                   int nrows) {
    float local = 0.0f;
    const int stride = gridDim.x * blockDim.x;
    for (int i = blockIdx.x * blockDim.x + threadIdx.x; i < nrows; i += stride) {
        const int b = bayes[i];
        // byte offset of q-row: 4*(i*100 + b*10) = 40*(10i+b) -> 8B aligned
        const float* qp = T + (size_t)i * (C * C) + (size_t)b * C;
        const int* pp = partial + (size_t)i * C;

        float s_neg = 0.0f, s_pos = 0.0f;
#pragma unroll
        for (int c = 0; c < C; c += 2) {
            const float2 qv = *reinterpret_cast<const float2*>(qp + c);
            const int2 pv = *reinterpret_cast<const int2*>(pp + c);
            if (pv.x == 0) s_neg += __expf(qv.x);
            else           s_pos += __expf(-qv.x);
            if (pv.y == 0) s_neg += __expf(qv.y);
            else           s_pos += __expf(-qv.y);
        }
        local += log1pf(s_neg * s_pos);
    }

    // wave(64) shuffle reduce
#pragma unroll
    for (int off = 32; off > 0; off >>= 1)
        local += __shfl_down(local, off, 64);

    __shared__ float wsum[4];  // 256 threads = 4 waves
    const int lane = threadIdx.x & 63;
    const int wid = threadIdx.x >> 6;
    if (lane == 0) wsum[wid] = local;
    __syncthreads();
    if (threadIdx.x == 0) {
        const float s = wsum[0] + wsum[1] + wsum[2] + wsum[3];
        atomicAdd(out, s * (1.0f / (float)NROWS));
    }
}

extern "C" void kernel_launch(void* const* d_in, const int* in_sizes, int n_in,
                              void* d_out, int out_size, void* d_ws, size_t ws_size,
                              hipStream_t stream) {
    const float* T = (const float*)d_in[0];
    const int* bayes = (const int*)d_in[1];
    const int* partial = (const int*)d_in[2];
    float* out = (float*)d_out;

    const int nrows = in_sizes[1];  // B (bayes is [B])

    // d_out is poisoned once before timing and never re-poisoned; zero it each call.
    hipMemsetAsync(d_out, 0, sizeof(float), stream);

    const int block = 256;
    const int grid = 2048;  // 8 blocks/CU on 256 CUs; grid-stride covers 1e6 rows
    lsep_kernel<<<grid, block, 0, stream>>>(T, bayes, partial, out, nrows);
}

// Round 2
// 88.442 us; speedup vs baseline: 1.1167x; 1.1167x over previous
//
#include <hip/hip_runtime.h>

// LSEP: loss = mean_i log1p( (sum_{n: partial=0} exp(q_n)) * (sum_{p: partial=1} exp(-q_p)) )
// q = T[i, bayes[i], :], T: [B,10,10] f32, bayes: [B] int32, partial: [B,10] int32.
// Layout: 16 lanes per row (10 active) -> coalesced 40-B segment gathers,
// ~6 cache lines per wave load instr instead of 64 (address-divergence fix).

#define NROWS 1000000
#define C 10
#define ROWS_PER_BLOCK 16              // 256 threads / 16 lanes-per-row
#define NBLOCKS (NROWS / ROWS_PER_BLOCK)  // 62500 exactly (1e6 = 62500*16)

__global__ __launch_bounds__(256) void lsep_k1(const float* __restrict__ T,
                                               const int* __restrict__ bayes,
                                               const int* __restrict__ partial,
                                               float* __restrict__ bsum) {
    const int tid = threadIdx.x;
    const int c   = tid & 15;          // element within row (active if < 10)
    const int rl  = tid >> 4;          // local row 0..15
    const int row = blockIdx.x * ROWS_PER_BLOCK + rl;

    const int b = bayes[row];          // 16 lanes, same address -> broadcast

    float e_neg = 0.0f, e_pos = 0.0f;
    if (c < C) {
        const float q = T[(size_t)row * (C * C) + (size_t)b * C + c];
        const int   p = partial[row * C + c];
        const float e = __expf(p == 0 ? q : -q);   // branchless sign
        e_neg = (p == 0) ? e : 0.0f;
        e_pos = (p == 0) ? 0.0f : e;
    }

    // sum the two partials across the 16-lane row group
#pragma unroll
    for (int m = 1; m < 16; m <<= 1) {
        e_neg += __shfl_xor(e_neg, m, 16);
        e_pos += __shfl_xor(e_pos, m, 16);
    }

    float val = (c == 0) ? log1pf(e_neg * e_pos) : 0.0f;

    // wave64 butterfly (only the four c==0 lanes carry nonzero)
#pragma unroll
    for (int m = 1; m < 64; m <<= 1)
        val += __shfl_xor(val, m, 64);

    __shared__ float wsum[4];
    const int lane = tid & 63, wid = tid >> 6;
    if (lane == 0) wsum[wid] = val;
    __syncthreads();
    if (tid == 0) bsum[blockIdx.x] = wsum[0] + wsum[1] + wsum[2] + wsum[3];
}

__global__ __launch_bounds__(1024) void lsep_k2(const float* __restrict__ bsum,
                                                float* __restrict__ out) {
    float s = 0.0f;
    for (int i = threadIdx.x; i < NBLOCKS; i += 1024) s += bsum[i];
#pragma unroll
    for (int m = 1; m < 64; m <<= 1) s += __shfl_xor(s, m, 64);
    __shared__ float wsum[16];
    const int lane = threadIdx.x & 63, wid = threadIdx.x >> 6;
    if (lane == 0) wsum[wid] = s;
    __syncthreads();
    if (threadIdx.x == 0) {
        float t = 0.0f;
#pragma unroll
        for (int w = 0; w < 16; ++w) t += wsum[w];
        out[0] = t * (1.0f / (float)NROWS);
    }
}

extern "C" void kernel_launch(void* const* d_in, const int* in_sizes, int n_in,
                              void* d_out, int out_size, void* d_ws, size_t ws_size,
                              hipStream_t stream) {
    const float* T       = (const float*)d_in[0];
    const int*   bayes   = (const int*)d_in[1];
    const int*   partial = (const int*)d_in[2];
    float*       out     = (float*)d_out;
    float*       bsum    = (float*)d_ws;   // 62500 floats, fully overwritten each call

    lsep_k1<<<NBLOCKS, 256, 0, stream>>>(T, bayes, partial, bsum);
    lsep_k2<<<1, 1024, 0, stream>>>(bsum, out);
}

// Round 3
// 74.433 us; speedup vs baseline: 1.3269x; 1.1882x over previous
//
#include <hip/hip_runtime.h>

// LSEP: loss = mean_i log1p( (sum_{n: partial=0} exp(q_n)) * (sum_{p: partial=1} exp(-q_p)) )
// q = T[i, bayes[i], :], T: [B,10,10] f32, bayes: [B] int32, partial: [B,10] int32.
//
// R3: latency/ILP fix. 16 lanes per row (coalesced 40-B gather), but each
// lane-group owns 50 rows processed in batches of 10 -> ~25 independent VMEM
// ops in flight per wave (was 2-3, a serialized bayes->T dependent chain).

#define NROWS 1000000
#define C 10
#define NBLK 1250
#define GPB 16                      // 16-lane groups per 256-thread block
#define NGROUPS (NBLK * GPB)        // 20000
#define NB 10                       // rows batched per iteration
#define NITER (NROWS / NGROUPS / NB) // 5  (20000*10*5 = 1e6 exactly)

__global__ __launch_bounds__(256) void lsep_k1(const float* __restrict__ T,
                                               const int* __restrict__ bayes,
                                               const int* __restrict__ partial,
                                               float* __restrict__ bsum) {
    const int tid = threadIdx.x;
    const int c   = tid & 15;                       // element lane (active if <10)
    const int g   = blockIdx.x * GPB + (tid >> 4);  // global row-group id

    float acc = 0.0f;   // only c==0 lanes accumulate nonzero

    for (int t = 0; t < NITER; ++t) {
        const int rbase = t * (NB * NGROUPS) + g;   // row(j) = rbase + j*NGROUPS

        int b[NB];
#pragma unroll
        for (int j = 0; j < NB; ++j)
            b[j] = bayes[rbase + j * NGROUPS];      // 10 independent broadcast loads

        float en[NB], ep[NB];
#pragma unroll
        for (int j = 0; j < NB; ++j) { en[j] = 0.0f; ep[j] = 0.0f; }

        if (c < C) {
#pragma unroll
            for (int j = 0; j < NB; ++j) {          // 20 independent gathers in flight
                const int row = rbase + j * NGROUPS;
                const float q = T[(size_t)row * (C * C) + b[j] * C + c];
                const int   p = partial[row * C + c];
                const float e = __expf(p == 0 ? q : -q);
                en[j] = (p == 0) ? e : 0.0f;
                ep[j] = (p == 0) ? 0.0f : e;
            }
        }

#pragma unroll
        for (int j = 0; j < NB; ++j) {
            float x = en[j], y = ep[j];
#pragma unroll
            for (int m = 1; m < 16; m <<= 1) {      // 16-lane butterfly (lanes >=10 hold 0)
                x += __shfl_xor(x, m, 16);
                y += __shfl_xor(y, m, 16);
            }
            if (c == 0) acc += log1pf(x * y);
        }
    }

    // block reduce: wave64 butterfly, then LDS across 4 waves
#pragma unroll
    for (int m = 1; m < 64; m <<= 1) acc += __shfl_xor(acc, m, 64);

    __shared__ float wsum[4];
    const int lane = tid & 63, wid = tid >> 6;
    if (lane == 0) wsum[wid] = acc;
    __syncthreads();
    if (tid == 0) bsum[blockIdx.x] = wsum[0] + wsum[1] + wsum[2] + wsum[3];
}

__global__ __launch_bounds__(256) void lsep_k2(const float* __restrict__ bsum,
                                               float* __restrict__ out) {
    float s = 0.0f;
    for (int i = threadIdx.x; i < NBLK; i += 256) s += bsum[i];   // 5 loads/thread
#pragma unroll
    for (int m = 1; m < 64; m <<= 1) s += __shfl_xor(s, m, 64);
    __shared__ float wsum[4];
    const int lane = threadIdx.x & 63, wid = threadIdx.x >> 6;
    if (lane == 0) wsum[wid] = s;
    __syncthreads();
    if (threadIdx.x == 0)
        out[0] = (wsum[0] + wsum[1] + wsum[2] + wsum[3]) * (1.0f / (float)NROWS);
}

extern "C" void kernel_launch(void* const* d_in, const int* in_sizes, int n_in,
                              void* d_out, int out_size, void* d_ws, size_t ws_size,
                              hipStream_t stream) {
    const float* T       = (const float*)d_in[0];
    const int*   bayes   = (const int*)d_in[1];
    const int*   partial = (const int*)d_in[2];
    float*       out     = (float*)d_out;
    float*       bsum    = (float*)d_ws;   // 1250 floats, fully overwritten each call

    lsep_k1<<<NBLK, 256, 0, stream>>>(T, bayes, partial, bsum);
    lsep_k2<<<1, 256, 0, stream>>>(bsum, out);
}

// Round 4
// 40.630 us; speedup vs baseline: 2.4309x; 1.8320x over previous
//
#include <hip/hip_runtime.h>

// LSEP: loss = mean_i log1p( (sum_{n: partial=0} exp(q_n)) * (sum_{p: partial=1} exp(-q_p)) )
// q = T[i, bayes[i], :], T: [B,10,10] f32, bayes: [B] int32, partial: [B,10] int32.
//
// R4: kill the shuffle-butterfly reduction. Stage gathered rows in LDS
// (coalesced-ish float2 gather, 8 rows/instr), then each lane reduces its OWN
// row at full 64/64 utilization (exp/log1p per-lane, zero shuffles in hot loop).
// DS ops per 64 rows: 128 -> ~22; VALU ~5x down. Should leave pure BW-bound.

#define NROWS  1000000
#define C      10
#define NCHUNK 15625   // 1e6 / 64 rows per chunk
#define NBLK   3125    // one-wave blocks
#define ITER   5       // chunks per block: 3125*5 = 15625 exactly

__global__ __launch_bounds__(64) void lsep_k1(const float* __restrict__ T,
                                              const int* __restrict__ bayes,
                                              const int* __restrict__ partial,
                                              float* __restrict__ bsum) {
    __shared__ float qs[64][12];   // gathered q rows, stride 48 B (16-B aligned rows)
    __shared__ int   ps[640];      // partial rows, flat [64][10]

    const int l  = threadIdx.x;
    const int c2 = l & 7;          // float2 slot within row (active if < 5)
    const int g  = l >> 3;         // row subgroup 0..7

    float acc = 0.0f;

    for (int t = 0; t < ITER; ++t) {
        const int rbase = (blockIdx.x * ITER + t) * 64;

        // ---- stage T gather: 8 instrs, 8 rows each, float2 per lane ----
#pragma unroll
        for (int k = 0; k < 8; ++k) {
            const int row = rbase + k * 8 + g;
            const int b   = bayes[row];              // 8 consecutive ints, group-broadcast
            if (c2 < 5) {
                const float2 v = *reinterpret_cast<const float2*>(
                    T + (size_t)row * (C * C) + b * C + 2 * c2);
                *reinterpret_cast<float2*>(&qs[k * 8 + g][2 * c2]) = v;
            }
        }

        // ---- stage partial: fully coalesced, identity LDS layout ----
#pragma unroll
        for (int i = 0; i < 5; ++i) {
            const int m = i * 64 + l;                // int2 index 0..319
            *reinterpret_cast<int2*>(&ps[2 * m]) =
                *reinterpret_cast<const int2*>(partial + (size_t)rbase * C + 2 * m);
        }

        __syncthreads();

        // ---- per-lane row reduce (lane l owns row rbase + l) ----
        float q[12];
        *reinterpret_cast<float4*>(&q[0]) = *reinterpret_cast<const float4*>(&qs[l][0]);
        *reinterpret_cast<float4*>(&q[4]) = *reinterpret_cast<const float4*>(&qs[l][4]);
        *reinterpret_cast<float2*>(&q[8]) = *reinterpret_cast<const float2*>(&qs[l][8]);

        int p[10];
#pragma unroll
        for (int i = 0; i < 5; ++i)
            *reinterpret_cast<int2*>(&p[2 * i]) =
                *reinterpret_cast<const int2*>(&ps[10 * l + 2 * i]);

        float sn = 0.0f, sp = 0.0f;
#pragma unroll
        for (int e = 0; e < C; ++e) {
            const float ex = __expf(p[e] == 0 ? q[e] : -q[e]);
            sn += (p[e] == 0) ? ex : 0.0f;
            sp += (p[e] == 0) ? 0.0f : ex;
        }
        acc += log1pf(sn * sp);

        __syncthreads();   // protect LDS before next iteration's writes
    }

    // wave64 reduce (6 steps, once per block)
#pragma unroll
    for (int m = 1; m < 64; m <<= 1) acc += __shfl_xor(acc, m, 64);
    if (l == 0) bsum[blockIdx.x] = acc;
}

__global__ __launch_bounds__(256) void lsep_k2(const float* __restrict__ bsum,
                                               float* __restrict__ out) {
    float s = 0.0f;
    for (int i = threadIdx.x; i < NBLK; i += 256) s += bsum[i];
#pragma unroll
    for (int m = 1; m < 64; m <<= 1) s += __shfl_xor(s, m, 64);
    __shared__ float wsum[4];
    const int lane = threadIdx.x & 63, wid = threadIdx.x >> 6;
    if (lane == 0) wsum[wid] = s;
    __syncthreads();
    if (threadIdx.x == 0)
        out[0] = (wsum[0] + wsum[1] + wsum[2] + wsum[3]) * (1.0f / (float)NROWS);
}

extern "C" void kernel_launch(void* const* d_in, const int* in_sizes, int n_in,
                              void* d_out, int out_size, void* d_ws, size_t ws_size,
                              hipStream_t stream) {
    const float* T       = (const float*)d_in[0];
    const int*   bayes   = (const int*)d_in[1];
    const int*   partial = (const int*)d_in[2];
    float*       out     = (float*)d_out;
    float*       bsum    = (float*)d_ws;   // 3125 floats, fully overwritten each call

    lsep_k1<<<NBLK, 64, 0, stream>>>(T, bayes, partial, bsum);
    lsep_k2<<<1, 256, 0, stream>>>(bsum, out);
}